// Round 3
// baseline (7280.749 us; speedup 1.0000x reference)
//
#include <hip/hip_runtime.h>
#include <hip/hip_bf16.h>

#define HDIM 300
#define FEAT 16
#define NL 5
#define BGR 4096
#define BNEPS 1e-5f

// ---------------- small elementwise kernels ----------------
__global__ void k_count_deg(const int* __restrict__ dst, float* __restrict__ degs, int E){
    int e = blockIdx.x*blockDim.x + threadIdx.x;
    if (e < E) unsafeAtomicAdd(&degs[dst[e]], 1.0f);
}
__global__ void k_deg_p1(float* __restrict__ degs, int N){
    int i = blockIdx.x*blockDim.x + threadIdx.x;
    if (i < N) degs[i] += 1.0f;
}
__global__ void k_init_vfeat(const float* __restrict__ vn, float* __restrict__ vfeat, int total){
    int t = blockIdx.x*blockDim.x + threadIdx.x;
    if (t < total) vfeat[t] = vn[t % HDIM];
}
__global__ void k_h0(const float* __restrict__ emb, const int* __restrict__ nt,
                     float* __restrict__ out, int total){
    int t = blockIdx.x*blockDim.x + threadIdx.x;
    if (t < total){ int i = t / HDIM; int c = t - i*HDIM; out[t] = emb[nt[i]*HDIM + c]; }
}
__global__ void k_add_vfeat(float* __restrict__ x, const float* __restrict__ vfeat,
                            const int* __restrict__ gid, int total){
    int t = blockIdx.x*blockDim.x + threadIdx.x;
    if (t < total){ int i = t / HDIM; int c = t - i*HDIM; x[t] += vfeat[gid[i]*HDIM + c]; }
}
__global__ void k_segsum(const float* __restrict__ x, float* __restrict__ vsum,
                         const int* __restrict__ gid, int total){
    int t = blockIdx.x*blockDim.x + threadIdx.x;
    if (t < total){ int i = t / HDIM; int c = t - i*HDIM; unsafeAtomicAdd(&vsum[gid[i]*HDIM + c], x[t]); }
}
__global__ void k_init_out(float* __restrict__ out, const float* __restrict__ hp,
                           const float* __restrict__ res, const float* __restrict__ degs, int total){
    int t = blockIdx.x*blockDim.x + threadIdx.x;
    if (t < total){
        int i = t / HDIM; int c = t - i*HDIM;
        float v = hp[t] + res[c];
        out[t] = fmaxf(v, 0.f) / degs[i];
    }
}
__global__ void k_addv(float* __restrict__ a, const float* __restrict__ b, int total){
    int t = blockIdx.x*blockDim.x + threadIdx.x;
    if (t < total) a[t] += b[t];
}

// ---------------- generic f32 GEMM: C[M,Ncol] = A[M,K] @ W[K,Ncol] + bias ----------------
// BM=128 BN=64 BK=16, 256 threads, 8x4 acc per thread.
__global__ __launch_bounds__(256) void k_gemm(const float* __restrict__ A, const float* __restrict__ W,
                                              const float* __restrict__ bias, float* __restrict__ C,
                                              int M, int K, int Ncol){
    __shared__ float As[16][132];
    __shared__ float Ws[16][64];
    int tid = threadIdx.x;
    int bm = blockIdx.x * 128;
    int bn = blockIdx.y * 64;
    int tx = tid & 15;
    int ty = tid >> 4;
    float acc[8][4];
#pragma unroll
    for (int i = 0; i < 8; i++)
#pragma unroll
        for (int j = 0; j < 4; j++) acc[i][j] = 0.f;
    int ka  = tid & 15;
    int ra0 = tid >> 4;
    int colw = tid & 63;
    int kw0  = tid >> 6;
    for (int k0 = 0; k0 < K; k0 += 16){
#pragma unroll
        for (int j = 0; j < 8; j++){
            int r = ra0 + j*16;
            int gm = bm + r, gk = k0 + ka;
            As[ka][r] = (gm < M && gk < K) ? A[(size_t)gm*K + gk] : 0.f;
        }
#pragma unroll
        for (int j = 0; j < 4; j++){
            int kk = kw0 + j*4;
            int gk = k0 + kk, gn = bn + colw;
            Ws[kk][colw] = (gk < K && gn < Ncol) ? W[(size_t)gk*Ncol + gn] : 0.f;
        }
        __syncthreads();
#pragma unroll
        for (int kk = 0; kk < 16; kk++){
            float a[8], b[4];
#pragma unroll
            for (int i = 0; i < 8; i++) a[i] = As[kk][ty*8 + i];
#pragma unroll
            for (int j = 0; j < 4; j++) b[j] = Ws[kk][tx*4 + j];
#pragma unroll
            for (int i = 0; i < 8; i++)
#pragma unroll
                for (int j = 0; j < 4; j++) acc[i][j] += a[i]*b[j];
        }
        __syncthreads();
    }
    float bb[4];
#pragma unroll
    for (int j = 0; j < 4; j++){ int gn = bn + tx*4 + j; bb[j] = (gn < Ncol) ? bias[gn] : 0.f; }
#pragma unroll
    for (int i = 0; i < 8; i++){
        int gm = bm + ty*8 + i;
        if (gm < M){
#pragma unroll
            for (int j = 0; j < 4; j++){
                int gn = bn + tx*4 + j;
                if (gn < Ncol) C[(size_t)gm*Ncol + gn] = acc[i][j] + bb[j];
            }
        }
    }
}

// ---------------- edge kernel: out[dst] += norm * relu(hp[src] + ef@We + be) ----------------
__global__ __launch_bounds__(256) void k_edge(const float* __restrict__ ef, const float* __restrict__ We,
                                              const float* __restrict__ be, const float* __restrict__ hp,
                                              const float* __restrict__ degs,
                                              const int* __restrict__ src, const int* __restrict__ dst,
                                              float* __restrict__ out, int E){
    __shared__ float WeL[FEAT*HDIM];
    __shared__ float beL[HDIM];
    for (int i = threadIdx.x; i < FEAT*HDIM; i += 256) WeL[i] = We[i];
    for (int i = threadIdx.x; i < HDIM; i += 256) beL[i] = be[i];
    __syncthreads();
    int lane = threadIdx.x & 63;
    int wave = threadIdx.x >> 6;
    for (int e = blockIdx.x*4 + wave; e < E; e += gridDim.x*4){
        int s = src[e], d = dst[e];
        float nrm = rsqrtf(degs[s]*degs[d]);
        float ev[FEAT];
#pragma unroll
        for (int k = 0; k < FEAT; k++) ev[k] = ef[(size_t)e*FEAT + k];
        const float* hrow = hp + (size_t)s*HDIM;
        float* orow = out + (size_t)d*HDIM;
        for (int c = lane; c < HDIM; c += 64){
            float acc = beL[c];
#pragma unroll
            for (int k = 0; k < FEAT; k++) acc += ev[k]*WeL[k*HDIM + c];
            float v = hrow[c] + acc;
            v = fmaxf(v, 0.f) * nrm;
            unsafeAtomicAdd(&orow[c], v);
        }
    }
}

// ---------------- batchnorm: column stats (f64), finalize, apply ----------------
__global__ void k_colstats(const float* __restrict__ x, int rows, int cols, int rpb,
                           double* __restrict__ stats){
    int c = blockIdx.y*blockDim.x + threadIdx.x;
    if (c >= cols) return;
    int r0 = blockIdx.x * rpb;
    int r1 = min(rows, r0 + rpb);
    double s = 0.0, s2 = 0.0;
    for (int r = r0; r < r1; ++r){
        float v = x[(size_t)r*cols + c];
        s += v; s2 += (double)v*v;
    }
    unsafeAtomicAdd(&stats[c], s);
    unsafeAtomicAdd(&stats[cols + c], s2);
}
__global__ void k_bn_finalize(const double* __restrict__ stats, const float* __restrict__ g,
                              const float* __restrict__ b, int cols, float rowsf, float* __restrict__ ss){
    int c = blockIdx.x*blockDim.x + threadIdx.x;
    if (c < cols){
        float mean = (float)(stats[c] / rowsf);
        float var  = (float)(stats[cols + c] / rowsf) - mean*mean;
        var = fmaxf(var, 0.f);
        float sc = g[c] * rsqrtf(var + BNEPS);
        ss[c] = sc;
        ss[cols + c] = b[c] - mean*sc;
    }
}
template<int COLS>
__global__ void k_bn_apply(float* __restrict__ x, const float* __restrict__ ss, int total, int relu){
    int t = blockIdx.x*blockDim.x + threadIdx.x;
    if (t < total){
        int c = t % COLS;
        float v = x[t]*ss[c] + ss[COLS + c];
        if (relu) v = fmaxf(v, 0.f);
        x[t] = v;
    }
}

extern "C" void kernel_launch(void* const* d_in, const int* in_sizes, int n_in,
                              void* d_out, int out_size, void* d_ws, size_t ws_size,
                              hipStream_t stream){
    const int*   node_types = (const int*)d_in[0];
    const float* edge_feats = (const float*)d_in[1];
    const int*   src        = (const int*)d_in[2];
    const int*   dst        = (const int*)d_in[3];
    const int*   gid        = (const int*)d_in[4];
    const float* node_emb   = (const float*)d_in[6];
    const float* Wn         = (const float*)d_in[7];
    const float* bn_lin     = (const float*)d_in[8];
    const float* We         = (const float*)d_in[9];
    const float* be         = (const float*)d_in[10];
    const float* res_emb    = (const float*)d_in[11];
    const float* bn_gamma   = (const float*)d_in[12];
    const float* bn_beta    = (const float*)d_in[13];
    const float* vn_emb     = (const float*)d_in[14];
    const float* vW1        = (const float*)d_in[15];
    const float* vb1        = (const float*)d_in[16];
    const float* vg1        = (const float*)d_in[17];
    const float* vbt1       = (const float*)d_in[18];
    const float* vW2        = (const float*)d_in[19];
    const float* vb2        = (const float*)d_in[20];
    const float* vg2        = (const float*)d_in[21];
    const float* vbt2       = (const float*)d_in[22];

    const int N = in_sizes[0];
    const int E = in_sizes[2];
    const int B = BGR;
    float* out = (float*)d_out;          // doubles as the h / X / agg accumulator

    char* w = (char*)d_ws;
    float*  hp    = (float*)w;  w += (size_t)N*HDIM*sizeof(float);
    float*  degs  = (float*)w;  w += (size_t)N*sizeof(float);
    float*  vfeat = (float*)w;  w += (size_t)B*HDIM*sizeof(float);
    float*  vsum  = (float*)w;  w += (size_t)B*HDIM*sizeof(float);
    float*  zbuf  = (float*)w;  w += (size_t)B*2*HDIM*sizeof(float);
    double* stats = (double*)w; w += (size_t)2*2*HDIM*sizeof(double);
    float*  ss    = (float*)w;  w += (size_t)2*2*HDIM*sizeof(float);

    const int NT = N*HDIM;
    const int BT = B*HDIM;
    auto cdiv = [](int a, int b){ return (a + b - 1)/b; };

    // setup: degrees, vfeat, h0
    hipMemsetAsync(degs, 0, (size_t)N*sizeof(float), stream);
    k_count_deg<<<cdiv(E,256),256,0,stream>>>(dst, degs, E);
    k_deg_p1<<<cdiv(N,256),256,0,stream>>>(degs, N);
    k_init_vfeat<<<cdiv(BT,256),256,0,stream>>>(vn_emb, vfeat, BT);
    k_h0<<<cdiv(NT,256),256,0,stream>>>(node_emb, node_types, out, NT);

    for (int l = 0; l < NL; l++){
        // X = h + vfeat[gid]   (in place on out)
        k_add_vfeat<<<cdiv(NT,256),256,0,stream>>>(out, vfeat, gid, NT);
        // hp = X @ Wn[l] + bn_lin[l]
        k_gemm<<<dim3(cdiv(N,128), cdiv(HDIM,64)),256,0,stream>>>(
            out, Wn + (size_t)l*HDIM*HDIM, bn_lin + (size_t)l*HDIM, hp, N, HDIM, HDIM);
        // virtual-node segment sum of X (must precede overwrite of out)
        if (l < NL-1){
            hipMemsetAsync(vsum, 0, (size_t)BT*sizeof(float), stream);
            k_segsum<<<cdiv(NT,256),256,0,stream>>>(out, vsum, gid, NT);
        }
        // out = relu(hp + res_emb[l]) / degs   (agg init, X destroyed)
        k_init_out<<<cdiv(NT,256),256,0,stream>>>(out, hp, res_emb + (size_t)l*HDIM, degs, NT);
        // out[dst] += norm * relu(hp[src] + ef@We[l] + be[l])
        k_edge<<<1024,256,0,stream>>>(edge_feats, We + (size_t)l*FEAT*HDIM, be + (size_t)l*HDIM,
                                      hp, degs, src, dst, out, E);
        // batchnorm (+relu except last layer)
        hipMemsetAsync(stats, 0, (size_t)2*HDIM*sizeof(double), stream);
        k_colstats<<<dim3(cdiv(N,256),1),320,0,stream>>>(out, N, HDIM, 256, stats);
        k_bn_finalize<<<1,320,0,stream>>>(stats, bn_gamma + (size_t)l*HDIM, bn_beta + (size_t)l*HDIM,
                                          HDIM, (float)N, ss);
        k_bn_apply<HDIM><<<cdiv(NT,256),256,0,stream>>>(out, ss, NT, (l < NL-1) ? 1 : 0);
        // virtual-node MLP update
        if (l < NL-1){
            k_addv<<<cdiv(BT,256),256,0,stream>>>(vsum, vfeat, BT);       // vtmp = segsum + vfeat
            k_gemm<<<dim3(cdiv(B,128), cdiv(2*HDIM,64)),256,0,stream>>>(
                vsum, vW1 + (size_t)l*HDIM*2*HDIM, vb1 + (size_t)l*2*HDIM, zbuf, B, HDIM, 2*HDIM);
            hipMemsetAsync(stats, 0, (size_t)2*2*HDIM*sizeof(double), stream);
            k_colstats<<<dim3(cdiv(B,256),2),320,0,stream>>>(zbuf, B, 2*HDIM, 256, stats);
            k_bn_finalize<<<1,640,0,stream>>>(stats, vg1 + (size_t)l*2*HDIM, vbt1 + (size_t)l*2*HDIM,
                                              2*HDIM, (float)B, ss);
            k_bn_apply<2*HDIM><<<cdiv(B*2*HDIM,256),256,0,stream>>>(zbuf, ss, B*2*HDIM, 1);
            k_gemm<<<dim3(cdiv(B,128), cdiv(HDIM,64)),256,0,stream>>>(
                zbuf, vW2 + (size_t)l*2*HDIM*HDIM, vb2 + (size_t)l*HDIM, vfeat, B, 2*HDIM, HDIM);
            hipMemsetAsync(stats, 0, (size_t)2*HDIM*sizeof(double), stream);
            k_colstats<<<dim3(cdiv(B,256),1),320,0,stream>>>(vfeat, B, HDIM, 256, stats);
            k_bn_finalize<<<1,320,0,stream>>>(stats, vg2 + (size_t)l*HDIM, vbt2 + (size_t)l*HDIM,
                                              HDIM, (float)B, ss);
            k_bn_apply<HDIM><<<cdiv(BT,256),256,0,stream>>>(vfeat, ss, BT, 1);
        }
    }
}

// Round 4
// 5851.814 us; speedup vs baseline: 1.2442x; 1.2442x over previous
//
#include <hip/hip_runtime.h>
#include <hip/hip_bf16.h>

#define HDIM 300
#define FEAT 16
#define NL 5
#define BGR 4096
#define BNEPS 1e-5f
#define KP1 320   // K=300 padded to multiple of 32

typedef __attribute__((ext_vector_type(8))) short s8v;
typedef __attribute__((ext_vector_type(4))) float f4v;

__device__ __forceinline__ unsigned short f2bu(float f){
    __hip_bfloat16 h = __float2bfloat16(f);
    return __builtin_bit_cast(unsigned short, h);
}

// ---------------- small elementwise kernels ----------------
__global__ void k_count_deg(const int* __restrict__ dst, float* __restrict__ degs, int E){
    int e = blockIdx.x*blockDim.x + threadIdx.x;
    if (e < E) unsafeAtomicAdd(&degs[dst[e]], 1.0f);
}
__global__ void k_deg_p1(float* __restrict__ degs, int N){
    int i = blockIdx.x*blockDim.x + threadIdx.x;
    if (i < N) degs[i] += 1.0f;
}
__global__ void k_init_vfeat(const float* __restrict__ vn, float* __restrict__ vfeat, int total){
    int t = blockIdx.x*blockDim.x + threadIdx.x;
    if (t < total) vfeat[t] = vn[t % HDIM];
}
// weight transpose+pad to bf16: Wt[n][kp] = W[k][n], zero for kp >= K
__global__ void k_wt(const float* __restrict__ W, unsigned short* __restrict__ Wt,
                     int K, int Ncol, int Kpad){
    int t = blockIdx.x*blockDim.x + threadIdx.x;
    if (t >= Ncol*Kpad) return;
    int n = t / Kpad, kp = t - n*Kpad;
    Wt[t] = (kp < K) ? f2bu(W[(size_t)kp*Ncol + n]) : (unsigned short)0;
}
// layer 0: X = emb[nt] + vfeat[gid]; write f32 X and padded bf16 Xb
__global__ void k_x0(const float* __restrict__ emb, const int* __restrict__ nt,
                     const float* __restrict__ vfeat, const int* __restrict__ gid,
                     float* __restrict__ X, unsigned short* __restrict__ Xb, int N){
    int t = blockIdx.x*blockDim.x + threadIdx.x;
    if (t >= N*KP1) return;
    int i = t / KP1, c = t - i*KP1;
    if (c < HDIM){
        float v = emb[nt[i]*HDIM + c] + vfeat[gid[i]*HDIM + c];
        X[(size_t)i*HDIM + c] = v;
        Xb[t] = f2bu(v);
    } else Xb[t] = 0;
}
// mid layers: X = relu(bn(X)) + vfeat[gid]; write f32 X and padded bf16 Xb
__global__ void k_bnvf(float* __restrict__ X, const float* __restrict__ ss,
                       const float* __restrict__ vfeat, const int* __restrict__ gid,
                       unsigned short* __restrict__ Xb, int N){
    int t = blockIdx.x*blockDim.x + threadIdx.x;
    if (t >= N*KP1) return;
    int i = t / KP1, c = t - i*KP1;
    if (c < HDIM){
        float v = X[(size_t)i*HDIM + c]*ss[c] + ss[HDIM + c];
        v = fmaxf(v, 0.f) + vfeat[gid[i]*HDIM + c];
        X[(size_t)i*HDIM + c] = v;
        Xb[t] = f2bu(v);
    } else Xb[t] = 0;
}
__global__ void k_segsum(const float* __restrict__ x, float* __restrict__ vsum,
                         const int* __restrict__ gid, int total){
    int t = blockIdx.x*blockDim.x + threadIdx.x;
    if (t < total){ int i = t / HDIM; int c = t - i*HDIM; unsafeAtomicAdd(&vsum[gid[i]*HDIM + c], x[t]); }
}
__global__ void k_addv(float* __restrict__ a, const float* __restrict__ b, int total){
    int t = blockIdx.x*blockDim.x + threadIdx.x;
    if (t < total) a[t] += b[t];
}

// ---------------- MFMA bf16 GEMM + fused epilogue ----------------
// C[M,Ncol] = A[M,Kpad]b @ W + bias ; if outb: outb = relu(C + res)/degs
// A: [M][lda] bf16 (zero-padded K). Wt: [Ncol][ldw] bf16 (k-contiguous, zero-padded).
__global__ __launch_bounds__(256) void k_gemm_mfma(
    const unsigned short* __restrict__ A, int lda,
    const unsigned short* __restrict__ Wt, int ldw,
    const float* __restrict__ bias,
    float* __restrict__ C, int M, int Kpad, int Ncol,
    const float* __restrict__ res, const float* __restrict__ degs,
    float* __restrict__ outb)
{
    __shared__ short As[128][40];   // stride 40 shorts = 80 B: 16B-aligned rows, banks tile cleanly
    __shared__ short Bs[64][40];
    int tid = threadIdx.x;
    int bm = blockIdx.x * 128;
    int bn = blockIdx.y * 64;
    int lane = tid & 63;
    int w = tid >> 6;
    int wm = w & 1, wn = w >> 1;
    int l15 = lane & 15, l4 = lane >> 4;
    f4v acc[4][2];
#pragma unroll
    for (int mi = 0; mi < 4; mi++)
#pragma unroll
        for (int ni = 0; ni < 2; ni++) acc[mi][ni] = (f4v){0.f,0.f,0.f,0.f};

    int arow = tid >> 1;           // 0..127
    int akc  = (tid & 1) * 2;      // {0,2} -> k-offsets {0,8} or {16,24}
    int gmA  = bm + arow;
    int brow = tid >> 2;           // 0..63
    int bkc  = tid & 3;
    int gnB  = bn + brow;
    const s8v zv = (s8v){0,0,0,0,0,0,0,0};

    for (int k0 = 0; k0 < Kpad; k0 += 32){
        __syncthreads();
        s8v a0 = zv, a1 = zv;
        if (gmA < M){
            const s8v* ap = (const s8v*)(A + (size_t)gmA*lda + k0 + akc*8);
            a0 = ap[0]; a1 = ap[1];
        }
        *(s8v*)&As[arow][akc*8]     = a0;
        *(s8v*)&As[arow][akc*8 + 8] = a1;
        s8v b0 = zv;
        if (gnB < Ncol) b0 = *(const s8v*)(Wt + (size_t)gnB*ldw + k0 + bkc*8);
        *(s8v*)&Bs[brow][bkc*8] = b0;
        __syncthreads();

        s8v af[4], bf[2];
#pragma unroll
        for (int mi = 0; mi < 4; mi++) af[mi] = *(const s8v*)&As[wm*64 + mi*16 + l15][l4*8];
#pragma unroll
        for (int ni = 0; ni < 2; ni++) bf[ni] = *(const s8v*)&Bs[wn*32 + ni*16 + l15][l4*8];
#pragma unroll
        for (int mi = 0; mi < 4; mi++)
#pragma unroll
            for (int ni = 0; ni < 2; ni++)
                acc[mi][ni] = __builtin_amdgcn_mfma_f32_16x16x32_bf16(af[mi], bf[ni], acc[mi][ni], 0, 0, 0);
    }

#pragma unroll
    for (int ni = 0; ni < 2; ni++){
        int col = bn + wn*32 + ni*16 + l15;
        if (col >= Ncol) continue;
        float bia = bias[col];
        float rs  = outb ? res[col] : 0.f;
#pragma unroll
        for (int mi = 0; mi < 4; mi++){
#pragma unroll
            for (int r = 0; r < 4; r++){
                int row = bm + wm*64 + mi*16 + l4*4 + r;
                if (row < M){
                    float val = acc[mi][ni][r] + bia;
                    C[(size_t)row*Ncol + col] = val;
                    if (outb)
                        outb[(size_t)row*Ncol + col] = fmaxf(val + rs, 0.f) / degs[row];
                }
            }
        }
    }
}

// ---------------- f32 VALU GEMM (vnode path): C = A@W + bias ----------------
__global__ __launch_bounds__(256) void k_gemm(const float* __restrict__ A, const float* __restrict__ W,
                                              const float* __restrict__ bias, float* __restrict__ C,
                                              int M, int K, int Ncol){
    __shared__ float As[16][132];
    __shared__ float Ws[16][64];
    int tid = threadIdx.x;
    int bm = blockIdx.x * 128;
    int bn = blockIdx.y * 64;
    int tx = tid & 15;
    int ty = tid >> 4;
    float acc[8][4];
#pragma unroll
    for (int i = 0; i < 8; i++)
#pragma unroll
        for (int j = 0; j < 4; j++) acc[i][j] = 0.f;
    int ka  = tid & 15;
    int ra0 = tid >> 4;
    int colw = tid & 63;
    int kw0  = tid >> 6;
    for (int k0 = 0; k0 < K; k0 += 16){
#pragma unroll
        for (int j = 0; j < 8; j++){
            int r = ra0 + j*16;
            int gm = bm + r, gk = k0 + ka;
            As[ka][r] = (gm < M && gk < K) ? A[(size_t)gm*K + gk] : 0.f;
        }
#pragma unroll
        for (int j = 0; j < 4; j++){
            int kk = kw0 + j*4;
            int gk = k0 + kk, gn = bn + colw;
            Ws[kk][colw] = (gk < K && gn < Ncol) ? W[(size_t)gk*Ncol + gn] : 0.f;
        }
        __syncthreads();
#pragma unroll
        for (int kk = 0; kk < 16; kk++){
            float a[8], b[4];
#pragma unroll
            for (int i = 0; i < 8; i++) a[i] = As[kk][ty*8 + i];
#pragma unroll
            for (int j = 0; j < 4; j++) b[j] = Ws[kk][tx*4 + j];
#pragma unroll
            for (int i = 0; i < 8; i++)
#pragma unroll
                for (int j = 0; j < 4; j++) acc[i][j] += a[i]*b[j];
        }
        __syncthreads();
    }
    float bb[4];
#pragma unroll
    for (int j = 0; j < 4; j++){ int gn = bn + tx*4 + j; bb[j] = (gn < Ncol) ? bias[gn] : 0.f; }
#pragma unroll
    for (int i = 0; i < 8; i++){
        int gm = bm + ty*8 + i;
        if (gm < M){
#pragma unroll
            for (int j = 0; j < 4; j++){
                int gn = bn + tx*4 + j;
                if (gn < Ncol) C[(size_t)gm*Ncol + gn] = acc[i][j] + bb[j];
            }
        }
    }
}

// ---------------- edge kernel: out[dst] += norm * relu(hp[src] + ef@We + be) ----------------
__global__ __launch_bounds__(256) void k_edge(const float* __restrict__ ef, const float* __restrict__ We,
                                              const float* __restrict__ be, const float* __restrict__ hp,
                                              const float* __restrict__ degs,
                                              const int* __restrict__ src, const int* __restrict__ dst,
                                              float* __restrict__ out, int E){
    __shared__ float WeL[FEAT*HDIM];
    __shared__ float beL[HDIM];
    for (int i = threadIdx.x; i < FEAT*HDIM; i += 256) WeL[i] = We[i];
    for (int i = threadIdx.x; i < HDIM; i += 256) beL[i] = be[i];
    __syncthreads();
    int lane = threadIdx.x & 63;
    int wave = threadIdx.x >> 6;
    for (int e = blockIdx.x*4 + wave; e < E; e += gridDim.x*4){
        int s = src[e], d = dst[e];
        float nrm = rsqrtf(degs[s]*degs[d]);
        float ev[FEAT];
#pragma unroll
        for (int k = 0; k < FEAT; k++) ev[k] = ef[(size_t)e*FEAT + k];
        const float* hrow = hp + (size_t)s*HDIM;
        float* orow = out + (size_t)d*HDIM;
        for (int c = lane; c < HDIM; c += 64){
            float acc = beL[c];
#pragma unroll
            for (int k = 0; k < FEAT; k++) acc += ev[k]*WeL[k*HDIM + c];
            float v = hrow[c] + acc;
            v = fmaxf(v, 0.f) * nrm;
            unsafeAtomicAdd(&orow[c], v);
        }
    }
}

// ---------------- batchnorm: column stats (f64), finalize, apply ----------------
__global__ void k_colstats(const float* __restrict__ x, int rows, int cols, int rpb,
                           double* __restrict__ stats){
    int c = blockIdx.y*blockDim.x + threadIdx.x;
    if (c >= cols) return;
    int r0 = blockIdx.x * rpb;
    int r1 = min(rows, r0 + rpb);
    double s = 0.0, s2 = 0.0;
    for (int r = r0; r < r1; ++r){
        float v = x[(size_t)r*cols + c];
        s += v; s2 += (double)v*v;
    }
    unsafeAtomicAdd(&stats[c], s);
    unsafeAtomicAdd(&stats[cols + c], s2);
}
__global__ void k_bn_finalize(const double* __restrict__ stats, const float* __restrict__ g,
                              const float* __restrict__ b, int cols, float rowsf, float* __restrict__ ss){
    int c = blockIdx.x*blockDim.x + threadIdx.x;
    if (c < cols){
        float mean = (float)(stats[c] / rowsf);
        float var  = (float)(stats[cols + c] / rowsf) - mean*mean;
        var = fmaxf(var, 0.f);
        float sc = g[c] * rsqrtf(var + BNEPS);
        ss[c] = sc;
        ss[cols + c] = b[c] - mean*sc;
    }
}
template<int COLS>
__global__ void k_bn_apply(float* __restrict__ x, const float* __restrict__ ss, int total, int relu){
    int t = blockIdx.x*blockDim.x + threadIdx.x;
    if (t < total){
        int c = t % COLS;
        float v = x[t]*ss[c] + ss[COLS + c];
        if (relu) v = fmaxf(v, 0.f);
        x[t] = v;
    }
}

extern "C" void kernel_launch(void* const* d_in, const int* in_sizes, int n_in,
                              void* d_out, int out_size, void* d_ws, size_t ws_size,
                              hipStream_t stream){
    const int*   node_types = (const int*)d_in[0];
    const float* edge_feats = (const float*)d_in[1];
    const int*   src        = (const int*)d_in[2];
    const int*   dst        = (const int*)d_in[3];
    const int*   gid        = (const int*)d_in[4];
    const float* node_emb   = (const float*)d_in[6];
    const float* Wn         = (const float*)d_in[7];
    const float* bn_lin     = (const float*)d_in[8];
    const float* We         = (const float*)d_in[9];
    const float* be         = (const float*)d_in[10];
    const float* res_emb    = (const float*)d_in[11];
    const float* bn_gamma   = (const float*)d_in[12];
    const float* bn_beta    = (const float*)d_in[13];
    const float* vn_emb     = (const float*)d_in[14];
    const float* vW1        = (const float*)d_in[15];
    const float* vb1        = (const float*)d_in[16];
    const float* vg1        = (const float*)d_in[17];
    const float* vbt1       = (const float*)d_in[18];
    const float* vW2        = (const float*)d_in[19];
    const float* vb2        = (const float*)d_in[20];
    const float* vg2        = (const float*)d_in[21];
    const float* vbt2       = (const float*)d_in[22];

    const int N = in_sizes[0];
    const int E = in_sizes[2];
    const int B = BGR;
    float* out = (float*)d_out;          // X / agg accumulator / final h

    char* w = (char*)d_ws;
    float*  hp    = (float*)w;  w += (size_t)N*HDIM*sizeof(float);
    float*  degs  = (float*)w;  w += (size_t)N*sizeof(float);
    float*  vfeat = (float*)w;  w += (size_t)B*HDIM*sizeof(float);
    float*  vsum  = (float*)w;  w += (size_t)B*HDIM*sizeof(float);
    float*  zbuf  = (float*)w;  w += (size_t)B*2*HDIM*sizeof(float);
    double* stats = (double*)w; w += (size_t)2*2*HDIM*sizeof(double);
    float*  ssn   = (float*)w;  w += (size_t)2*HDIM*sizeof(float);
    float*  ssv   = (float*)w;  w += (size_t)2*2*HDIM*sizeof(float);
    unsigned short* Xb  = (unsigned short*)w; w += (size_t)N*KP1*sizeof(unsigned short);
    unsigned short* Wnb = (unsigned short*)w; w += (size_t)NL*HDIM*KP1*sizeof(unsigned short);

    const int NT = N*HDIM;
    const int BT = B*HDIM;
    auto cdiv = [](int a, int b){ return (a + b - 1)/b; };

    // setup: degrees, vfeat, bf16 weights, X0
    hipMemsetAsync(degs, 0, (size_t)N*sizeof(float), stream);
    k_count_deg<<<cdiv(E,256),256,0,stream>>>(dst, degs, E);
    k_deg_p1<<<cdiv(N,256),256,0,stream>>>(degs, N);
    k_init_vfeat<<<cdiv(BT,256),256,0,stream>>>(vn_emb, vfeat, BT);
    for (int l = 0; l < NL; l++)
        k_wt<<<cdiv(HDIM*KP1,256),256,0,stream>>>(Wn + (size_t)l*HDIM*HDIM,
                                                  Wnb + (size_t)l*HDIM*KP1, HDIM, HDIM, KP1);
    k_x0<<<cdiv(N*KP1,256),256,0,stream>>>(node_emb, node_types, vfeat, gid, out, Xb, N);

    for (int l = 0; l < NL; l++){
        // segment-sum of X for vnode (before out is overwritten)
        if (l < NL-1){
            hipMemsetAsync(vsum, 0, (size_t)BT*sizeof(float), stream);
            k_segsum<<<cdiv(NT,256),256,0,stream>>>(out, vsum, gid, NT);
        }
        // hp = Xb @ Wn[l] + bn_lin[l] ; out = relu(hp + res)/degs  (fused)
        k_gemm_mfma<<<dim3(cdiv(N,128), cdiv(HDIM,64)),256,0,stream>>>(
            Xb, KP1, Wnb + (size_t)l*HDIM*KP1, KP1, bn_lin + (size_t)l*HDIM,
            hp, N, KP1, HDIM, res_emb + (size_t)l*HDIM, degs, out);
        // out[dst] += norm * relu(hp[src] + ef@We[l] + be[l])
        k_edge<<<1024,256,0,stream>>>(edge_feats, We + (size_t)l*FEAT*HDIM, be + (size_t)l*HDIM,
                                      hp, degs, src, dst, out, E);
        // node BN stats
        hipMemsetAsync(stats, 0, (size_t)2*HDIM*sizeof(double), stream);
        k_colstats<<<dim3(cdiv(N,256),1),320,0,stream>>>(out, N, HDIM, 256, stats);
        k_bn_finalize<<<1,320,0,stream>>>(stats, bn_gamma + (size_t)l*HDIM, bn_beta + (size_t)l*HDIM,
                                          HDIM, (float)N, ssn);
        if (l < NL-1){
            // virtual-node MLP (f32 path)
            k_addv<<<cdiv(BT,256),256,0,stream>>>(vsum, vfeat, BT);
            k_gemm<<<dim3(cdiv(B,128), cdiv(2*HDIM,64)),256,0,stream>>>(
                vsum, vW1 + (size_t)l*HDIM*2*HDIM, vb1 + (size_t)l*2*HDIM, zbuf, B, HDIM, 2*HDIM);
            hipMemsetAsync(stats, 0, (size_t)2*2*HDIM*sizeof(double), stream);
            k_colstats<<<dim3(cdiv(B,256),2),320,0,stream>>>(zbuf, B, 2*HDIM, 256, stats);
            k_bn_finalize<<<1,640,0,stream>>>(stats, vg1 + (size_t)l*2*HDIM, vbt1 + (size_t)l*2*HDIM,
                                              2*HDIM, (float)B, ssv);
            k_bn_apply<2*HDIM><<<cdiv(B*2*HDIM,256),256,0,stream>>>(zbuf, ssv, B*2*HDIM, 1);
            k_gemm<<<dim3(cdiv(B,128), cdiv(HDIM,64)),256,0,stream>>>(
                zbuf, vW2 + (size_t)l*2*HDIM*HDIM, vb2 + (size_t)l*HDIM, vfeat, B, 2*HDIM, HDIM);
            hipMemsetAsync(stats, 0, (size_t)2*HDIM*sizeof(double), stream);
            k_colstats<<<dim3(cdiv(B,256),1),320,0,stream>>>(vfeat, B, HDIM, 256, stats);
            k_bn_finalize<<<1,320,0,stream>>>(stats, vg2 + (size_t)l*HDIM, vbt2 + (size_t)l*HDIM,
                                              HDIM, (float)B, ssv);
            k_bn_apply<HDIM><<<cdiv(BT,256),256,0,stream>>>(vfeat, ssv, BT, 1);
            // X_{l+1} = relu(bn(out)) + vfeat[gid]  (fused, also writes bf16 Xb)
            k_bnvf<<<cdiv(N*KP1,256),256,0,stream>>>(out, ssn, vfeat, gid, Xb, N);
        } else {
            k_bn_apply<HDIM><<<cdiv(NT,256),256,0,stream>>>(out, ssn, NT, 0);
        }
    }
}

// Round 5
// 5093.987 us; speedup vs baseline: 1.4293x; 1.1488x over previous
//
#include <hip/hip_runtime.h>
#include <hip/hip_bf16.h>

#define HDIM 300
#define FEAT 16
#define NL 5
#define BGR 4096
#define BNEPS 1e-5f
#define KP1 320   // K=300 padded to multiple of 32

typedef __attribute__((ext_vector_type(8))) short s8v;
typedef __attribute__((ext_vector_type(4))) float f4v;

__device__ __forceinline__ unsigned short f2bu(float f){
    __hip_bfloat16 h = __float2bfloat16(f);
    return __builtin_bit_cast(unsigned short, h);
}

// ---------------- setup kernels ----------------
__global__ void k_count_deg(const int* __restrict__ dst, int* __restrict__ cnt, int E){
    int e = blockIdx.x*blockDim.x + threadIdx.x;
    if (e < E) atomicAdd(&cnt[dst[e]], 1);
}
__global__ void k_deg(const int* __restrict__ cnt, float* __restrict__ degs, int N){
    int i = blockIdx.x*blockDim.x + threadIdx.x;
    if (i < N) degs[i] = (float)cnt[i] + 1.0f;
}
// --- exclusive scan of cnt -> off (off[N]=E), 3 phases ---
__global__ void k_scan_partial(const int* __restrict__ cnt, int* __restrict__ part, int N){
    __shared__ int sm[256];
    int i = blockIdx.x*256 + threadIdx.x;
    sm[threadIdx.x] = (i < N) ? cnt[i] : 0;
    __syncthreads();
    for (int s = 128; s > 0; s >>= 1){
        if (threadIdx.x < s) sm[threadIdx.x] += sm[threadIdx.x + s];
        __syncthreads();
    }
    if (threadIdx.x == 0) part[blockIdx.x] = sm[0];
}
__global__ void k_scan_blocks(int* __restrict__ part, int nb){
    __shared__ int sm[512];
    int t = threadIdx.x;
    int v = (t < nb) ? part[t] : 0;
    sm[t] = v; __syncthreads();
    for (int o = 1; o < 512; o <<= 1){
        int x = (t >= o) ? sm[t - o] : 0;
        __syncthreads();
        sm[t] += x;
        __syncthreads();
    }
    if (t < nb) part[t] = sm[t] - v;   // exclusive
}
__global__ void k_scan_final(const int* __restrict__ cnt, const int* __restrict__ part,
                             int* __restrict__ off, int N){
    __shared__ int sm[256];
    int i = blockIdx.x*256 + threadIdx.x;
    int v = (i < N) ? cnt[i] : 0;
    sm[threadIdx.x] = v; __syncthreads();
    for (int o = 1; o < 256; o <<= 1){
        int x = (threadIdx.x >= o) ? sm[threadIdx.x - o] : 0;
        __syncthreads();
        sm[threadIdx.x] += x;
        __syncthreads();
    }
    if (i < N){
        off[i] = part[blockIdx.x] + sm[threadIdx.x] - v;
        if (i == N-1) off[N] = part[blockIdx.x] + sm[threadIdx.x];
    }
}
__global__ void k_fill(const int* __restrict__ dst, const int* __restrict__ off,
                       int* __restrict__ fillc, int* __restrict__ eid, int E){
    int e = blockIdx.x*blockDim.x + threadIdx.x;
    if (e < E){
        int d = dst[e];
        int p = off[d] + atomicAdd(&fillc[d], 1);
        eid[p] = e;
    }
}
__global__ void k_init_vfeat(const float* __restrict__ vn, float* __restrict__ vfeat, int total){
    int t = blockIdx.x*blockDim.x + threadIdx.x;
    if (t < total) vfeat[t] = vn[t % HDIM];
}
// weight transpose+pad to bf16: Wt[n][kp] = W[k][n]
__global__ void k_wt(const float* __restrict__ W, unsigned short* __restrict__ Wt,
                     int K, int Ncol, int Kpad){
    int t = blockIdx.x*blockDim.x + threadIdx.x;
    if (t >= Ncol*Kpad) return;
    int n = t / Kpad, kp = t - n*Kpad;
    Wt[t] = (kp < K) ? f2bu(W[(size_t)kp*Ncol + n]) : (unsigned short)0;
}
// layer 0: X = emb[nt] + vfeat[gid]; write f32 X, bf16 Xb, and segsum into vsum
__global__ void k_x0(const float* __restrict__ emb, const int* __restrict__ nt,
                     const float* __restrict__ vfeat, const int* __restrict__ gid,
                     float* __restrict__ X, unsigned short* __restrict__ Xb,
                     float* __restrict__ vsum, int N){
    int t = blockIdx.x*blockDim.x + threadIdx.x;
    if (t >= N*KP1) return;
    int i = t / KP1, c = t - i*KP1;
    if (c < HDIM){
        float v = emb[nt[i]*HDIM + c] + vfeat[gid[i]*HDIM + c];
        X[(size_t)i*HDIM + c] = v;
        Xb[t] = f2bu(v);
        unsafeAtomicAdd(&vsum[gid[i]*HDIM + c], v);
    } else Xb[t] = 0;
}
// mid layers: X = relu(bn(X)) + vfeat[gid]; write f32 X, bf16 Xb, segsum into vsum
__global__ void k_bnvf(float* __restrict__ X, const float* __restrict__ ss,
                       const float* __restrict__ vfeat, const int* __restrict__ gid,
                       unsigned short* __restrict__ Xb, float* __restrict__ vsum, int N){
    int t = blockIdx.x*blockDim.x + threadIdx.x;
    if (t >= N*KP1) return;
    int i = t / KP1, c = t - i*KP1;
    if (c < HDIM){
        float v = X[(size_t)i*HDIM + c]*ss[c] + ss[HDIM + c];
        v = fmaxf(v, 0.f) + vfeat[gid[i]*HDIM + c];
        X[(size_t)i*HDIM + c] = v;
        Xb[t] = f2bu(v);
        unsafeAtomicAdd(&vsum[gid[i]*HDIM + c], v);
    } else Xb[t] = 0;
}
__global__ void k_addv(float* __restrict__ a, const float* __restrict__ b, int total){
    int t = blockIdx.x*blockDim.x + threadIdx.x;
    if (t < total) a[t] += b[t];
}

// ---------------- MFMA bf16 GEMM: C = A@Wt^T + bias ----------------
__global__ __launch_bounds__(256) void k_gemm_mfma(
    const unsigned short* __restrict__ A, int lda,
    const unsigned short* __restrict__ Wt, int ldw,
    const float* __restrict__ bias,
    float* __restrict__ C, int M, int Kpad, int Ncol)
{
    __shared__ short As[128][40];
    __shared__ short Bs[64][40];
    int tid = threadIdx.x;
    int bm = blockIdx.x * 128;
    int bn = blockIdx.y * 64;
    int lane = tid & 63;
    int w = tid >> 6;
    int wm = w & 1, wn = w >> 1;
    int l15 = lane & 15, l4 = lane >> 4;
    f4v acc[4][2];
#pragma unroll
    for (int mi = 0; mi < 4; mi++)
#pragma unroll
        for (int ni = 0; ni < 2; ni++) acc[mi][ni] = (f4v){0.f,0.f,0.f,0.f};

    int arow = tid >> 1;
    int akc  = (tid & 1) * 2;
    int gmA  = bm + arow;
    int brow = tid >> 2;
    int bkc  = tid & 3;
    int gnB  = bn + brow;
    const s8v zv = (s8v){0,0,0,0,0,0,0,0};

    for (int k0 = 0; k0 < Kpad; k0 += 32){
        __syncthreads();
        s8v a0 = zv, a1 = zv;
        if (gmA < M){
            const s8v* ap = (const s8v*)(A + (size_t)gmA*lda + k0 + akc*8);
            a0 = ap[0]; a1 = ap[1];
        }
        *(s8v*)&As[arow][akc*8]     = a0;
        *(s8v*)&As[arow][akc*8 + 8] = a1;
        s8v b0 = zv;
        if (gnB < Ncol) b0 = *(const s8v*)(Wt + (size_t)gnB*ldw + k0 + bkc*8);
        *(s8v*)&Bs[brow][bkc*8] = b0;
        __syncthreads();

        s8v af[4], bf[2];
#pragma unroll
        for (int mi = 0; mi < 4; mi++) af[mi] = *(const s8v*)&As[wm*64 + mi*16 + l15][l4*8];
#pragma unroll
        for (int ni = 0; ni < 2; ni++) bf[ni] = *(const s8v*)&Bs[wn*32 + ni*16 + l15][l4*8];
#pragma unroll
        for (int mi = 0; mi < 4; mi++)
#pragma unroll
            for (int ni = 0; ni < 2; ni++)
                acc[mi][ni] = __builtin_amdgcn_mfma_f32_16x16x32_bf16(af[mi], bf[ni], acc[mi][ni], 0, 0, 0);
    }

#pragma unroll
    for (int ni = 0; ni < 2; ni++){
        int col = bn + wn*32 + ni*16 + l15;
        if (col >= Ncol) continue;
        float bia = bias[col];
#pragma unroll
        for (int mi = 0; mi < 4; mi++){
#pragma unroll
            for (int r = 0; r < 4; r++){
                int row = bm + wm*64 + mi*16 + l4*4 + r;
                if (row < M) C[(size_t)row*Ncol + col] = acc[mi][ni][r] + bia;
            }
        }
    }
}

// ---------------- f32 VALU GEMM (vnode path) ----------------
__global__ __launch_bounds__(256) void k_gemm(const float* __restrict__ A, const float* __restrict__ W,
                                              const float* __restrict__ bias, float* __restrict__ C,
                                              int M, int K, int Ncol){
    __shared__ float As[16][132];
    __shared__ float Ws[16][64];
    int tid = threadIdx.x;
    int bm = blockIdx.x * 128;
    int bn = blockIdx.y * 64;
    int tx = tid & 15;
    int ty = tid >> 4;
    float acc[8][4];
#pragma unroll
    for (int i = 0; i < 8; i++)
#pragma unroll
        for (int j = 0; j < 4; j++) acc[i][j] = 0.f;
    int ka  = tid & 15;
    int ra0 = tid >> 4;
    int colw = tid & 63;
    int kw0  = tid >> 6;
    for (int k0 = 0; k0 < K; k0 += 16){
#pragma unroll
        for (int j = 0; j < 8; j++){
            int r = ra0 + j*16;
            int gm = bm + r, gk = k0 + ka;
            As[ka][r] = (gm < M && gk < K) ? A[(size_t)gm*K + gk] : 0.f;
        }
#pragma unroll
        for (int j = 0; j < 4; j++){
            int kk = kw0 + j*4;
            int gk = k0 + kk, gn = bn + colw;
            Ws[kk][colw] = (gk < K && gn < Ncol) ? W[(size_t)gk*Ncol + gn] : 0.f;
        }
        __syncthreads();
#pragma unroll
        for (int kk = 0; kk < 16; kk++){
            float a[8], b[4];
#pragma unroll
            for (int i = 0; i < 8; i++) a[i] = As[kk][ty*8 + i];
#pragma unroll
            for (int j = 0; j < 4; j++) b[j] = Ws[kk][tx*4 + j];
#pragma unroll
            for (int i = 0; i < 8; i++)
#pragma unroll
                for (int j = 0; j < 4; j++) acc[i][j] += a[i]*b[j];
        }
        __syncthreads();
    }
    float bb[4];
#pragma unroll
    for (int j = 0; j < 4; j++){ int gn = bn + tx*4 + j; bb[j] = (gn < Ncol) ? bias[gn] : 0.f; }
#pragma unroll
    for (int i = 0; i < 8; i++){
        int gm = bm + ty*8 + i;
        if (gm < M){
#pragma unroll
            for (int j = 0; j < 4; j++){
                int gn = bn + tx*4 + j;
                if (gn < Ncol) C[(size_t)gm*Ncol + gn] = acc[i][j] + bb[j];
            }
        }
    }
}

// ---------------- CSR aggregation (replaces scatter-atomic k_edge + k_init_out) ----------------
// out[d] = relu(hp[d]+res)/deg[d] + sum_{e: dst=d} rsqrt(deg[src]*deg[d]) * relu(hp[src] + ef[e]@We + be)
__global__ __launch_bounds__(256) void k_agg(
    const float* __restrict__ hp, const float* __restrict__ res, const float* __restrict__ degs,
    const float* __restrict__ ef, const float* __restrict__ We, const float* __restrict__ be,
    const int* __restrict__ off, const int* __restrict__ eid, const int* __restrict__ src,
    float* __restrict__ out, int N)
{
    __shared__ float WeL[FEAT*HDIM];
    __shared__ float beL[HDIM];
    for (int i = threadIdx.x; i < FEAT*HDIM; i += 256) WeL[i] = We[i];
    for (int i = threadIdx.x; i < HDIM; i += 256) beL[i] = be[i];
    __syncthreads();
    int lane = threadIdx.x & 63;
    int wave = threadIdx.x >> 6;
    int d = blockIdx.x*4 + wave;
    if (d >= N) return;
    float dd = degs[d];
    float acc[5];
    const float* hrowd = hp + (size_t)d*HDIM;
#pragma unroll
    for (int i = 0; i < 5; i++){
        int c = lane + 64*i;
        acc[i] = (c < HDIM) ? fmaxf(hrowd[c] + res[c], 0.f) / dd : 0.f;
    }
    int e0 = off[d], e1 = off[d+1];
    for (int p = e0; p < e1; ++p){
        int e = eid[p];
        int s = src[e];
        float nrm = rsqrtf(degs[s]*dd);
        float ev[FEAT];
#pragma unroll
        for (int k = 0; k < FEAT; k++) ev[k] = ef[(size_t)e*FEAT + k];
        const float* hrow = hp + (size_t)s*HDIM;
#pragma unroll
        for (int i = 0; i < 5; i++){
            int c = lane + 64*i;
            if (c < HDIM){
                float a = beL[c];
#pragma unroll
                for (int k = 0; k < FEAT; k++) a += ev[k]*WeL[k*HDIM + c];
                acc[i] += fmaxf(hrow[c] + a, 0.f) * nrm;
            }
        }
    }
    float* orow = out + (size_t)d*HDIM;
#pragma unroll
    for (int i = 0; i < 5; i++){
        int c = lane + 64*i;
        if (c < HDIM) orow[c] = acc[i];
    }
}

// ---------------- batchnorm: column stats (f64), finalize, apply ----------------
__global__ void k_colstats(const float* __restrict__ x, int rows, int cols, int rpb,
                           double* __restrict__ stats){
    int c = blockIdx.y*blockDim.x + threadIdx.x;
    if (c >= cols) return;
    int r0 = blockIdx.x * rpb;
    int r1 = min(rows, r0 + rpb);
    double s = 0.0, s2 = 0.0;
    for (int r = r0; r < r1; ++r){
        float v = x[(size_t)r*cols + c];
        s += v; s2 += (double)v*v;
    }
    unsafeAtomicAdd(&stats[c], s);
    unsafeAtomicAdd(&stats[cols + c], s2);
}
__global__ void k_bn_finalize(const double* __restrict__ stats, const float* __restrict__ g,
                              const float* __restrict__ b, int cols, float rowsf, float* __restrict__ ss){
    int c = blockIdx.x*blockDim.x + threadIdx.x;
    if (c < cols){
        float mean = (float)(stats[c] / rowsf);
        float var  = (float)(stats[cols + c] / rowsf) - mean*mean;
        var = fmaxf(var, 0.f);
        float sc = g[c] * rsqrtf(var + BNEPS);
        ss[c] = sc;
        ss[cols + c] = b[c] - mean*sc;
    }
}
template<int COLS>
__global__ void k_bn_apply(float* __restrict__ x, const float* __restrict__ ss, int total, int relu){
    int t = blockIdx.x*blockDim.x + threadIdx.x;
    if (t < total){
        int c = t % COLS;
        float v = x[t]*ss[c] + ss[COLS + c];
        if (relu) v = fmaxf(v, 0.f);
        x[t] = v;
    }
}

extern "C" void kernel_launch(void* const* d_in, const int* in_sizes, int n_in,
                              void* d_out, int out_size, void* d_ws, size_t ws_size,
                              hipStream_t stream){
    const int*   node_types = (const int*)d_in[0];
    const float* edge_feats = (const float*)d_in[1];
    const int*   src        = (const int*)d_in[2];
    const int*   dst        = (const int*)d_in[3];
    const int*   gid        = (const int*)d_in[4];
    const float* node_emb   = (const float*)d_in[6];
    const float* Wn         = (const float*)d_in[7];
    const float* bn_lin     = (const float*)d_in[8];
    const float* We         = (const float*)d_in[9];
    const float* be         = (const float*)d_in[10];
    const float* res_emb    = (const float*)d_in[11];
    const float* bn_gamma   = (const float*)d_in[12];
    const float* bn_beta    = (const float*)d_in[13];
    const float* vn_emb     = (const float*)d_in[14];
    const float* vW1        = (const float*)d_in[15];
    const float* vb1        = (const float*)d_in[16];
    const float* vg1        = (const float*)d_in[17];
    const float* vbt1       = (const float*)d_in[18];
    const float* vW2        = (const float*)d_in[19];
    const float* vb2        = (const float*)d_in[20];
    const float* vg2        = (const float*)d_in[21];
    const float* vbt2       = (const float*)d_in[22];

    const int N = in_sizes[0];
    const int E = in_sizes[2];
    const int B = BGR;
    float* out = (float*)d_out;          // X / agg / final h

    char* w = (char*)d_ws;
    float*  hp    = (float*)w;  w += (size_t)N*HDIM*sizeof(float);
    float*  degs  = (float*)w;  w += (size_t)N*sizeof(float);
    float*  vfeat = (float*)w;  w += (size_t)B*HDIM*sizeof(float);
    float*  vsum  = (float*)w;  w += (size_t)B*HDIM*sizeof(float);
    float*  zbuf  = (float*)w;  w += (size_t)B*2*HDIM*sizeof(float);
    double* stats = (double*)w; w += (size_t)2*2*HDIM*sizeof(double);
    float*  ssn   = (float*)w;  w += (size_t)2*HDIM*sizeof(float);
    float*  ssv   = (float*)w;  w += (size_t)2*2*HDIM*sizeof(float);
    int*    cnt   = (int*)w;    w += (size_t)N*sizeof(int);
    int*    coff  = (int*)w;    w += (size_t)(N+1)*sizeof(int);
    int*    fillc = (int*)w;    w += (size_t)N*sizeof(int);
    int*    eid   = (int*)w;    w += (size_t)E*sizeof(int);
    int*    part  = (int*)w;    w += (size_t)512*sizeof(int);
    unsigned short* Xb  = (unsigned short*)w; w += (size_t)N*KP1*sizeof(unsigned short);
    unsigned short* Wnb = (unsigned short*)w; w += (size_t)NL*HDIM*KP1*sizeof(unsigned short);

    const int NT = N*HDIM;
    const int BT = B*HDIM;
    auto cdiv = [](int a, int b){ return (a + b - 1)/b; };
    const int nb = cdiv(N, 256);

    // ---- setup: degrees + CSR ----
    hipMemsetAsync(cnt, 0, (size_t)N*sizeof(int), stream);
    k_count_deg<<<cdiv(E,256),256,0,stream>>>(dst, cnt, E);
    k_deg<<<nb,256,0,stream>>>(cnt, degs, N);
    k_scan_partial<<<nb,256,0,stream>>>(cnt, part, N);
    k_scan_blocks<<<1,512,0,stream>>>(part, nb);
    k_scan_final<<<nb,256,0,stream>>>(cnt, part, coff, N);
    hipMemsetAsync(fillc, 0, (size_t)N*sizeof(int), stream);
    k_fill<<<cdiv(E,256),256,0,stream>>>(dst, coff, fillc, eid, E);
    // ---- setup: weights, vfeat, X0 (+segsum into vsum) ----
    k_init_vfeat<<<cdiv(BT,256),256,0,stream>>>(vn_emb, vfeat, BT);
    for (int l = 0; l < NL; l++)
        k_wt<<<cdiv(HDIM*KP1,256),256,0,stream>>>(Wn + (size_t)l*HDIM*HDIM,
                                                  Wnb + (size_t)l*HDIM*KP1, HDIM, HDIM, KP1);
    hipMemsetAsync(vsum, 0, (size_t)BT*sizeof(float), stream);
    k_x0<<<cdiv(N*KP1,256),256,0,stream>>>(node_emb, node_types, vfeat, gid, out, Xb, vsum, N);

    for (int l = 0; l < NL; l++){
        // hp = Xb @ Wn[l] + bn_lin[l]
        k_gemm_mfma<<<dim3(cdiv(N,128), cdiv(HDIM,64)),256,0,stream>>>(
            Xb, KP1, Wnb + (size_t)l*HDIM*KP1, KP1, bn_lin + (size_t)l*HDIM, hp, N, KP1, HDIM);
        // out = residual + CSR-aggregated edge messages
        k_agg<<<cdiv(N,4),256,0,stream>>>(hp, res_emb + (size_t)l*HDIM, degs,
                                          edge_feats, We + (size_t)l*FEAT*HDIM, be + (size_t)l*HDIM,
                                          coff, eid, src, out, N);
        // node BN stats
        hipMemsetAsync(stats, 0, (size_t)2*HDIM*sizeof(double), stream);
        k_colstats<<<dim3(cdiv(N,256),1),320,0,stream>>>(out, N, HDIM, 256, stats);
        k_bn_finalize<<<1,320,0,stream>>>(stats, bn_gamma + (size_t)l*HDIM, bn_beta + (size_t)l*HDIM,
                                          HDIM, (float)N, ssn);
        if (l < NL-1){
            // virtual-node MLP (vsum was filled by k_x0 / previous k_bnvf)
            k_addv<<<cdiv(BT,256),256,0,stream>>>(vsum, vfeat, BT);
            k_gemm<<<dim3(cdiv(B,128), cdiv(2*HDIM,64)),256,0,stream>>>(
                vsum, vW1 + (size_t)l*HDIM*2*HDIM, vb1 + (size_t)l*2*HDIM, zbuf, B, HDIM, 2*HDIM);
            hipMemsetAsync(stats, 0, (size_t)2*2*HDIM*sizeof(double), stream);
            k_colstats<<<dim3(cdiv(B,256),2),320,0,stream>>>(zbuf, B, 2*HDIM, 256, stats);
            k_bn_finalize<<<1,640,0,stream>>>(stats, vg1 + (size_t)l*2*HDIM, vbt1 + (size_t)l*2*HDIM,
                                              2*HDIM, (float)B, ssv);
            k_bn_apply<2*HDIM><<<cdiv(B*2*HDIM,256),256,0,stream>>>(zbuf, ssv, B*2*HDIM, 1);
            k_gemm<<<dim3(cdiv(B,128), cdiv(HDIM,64)),256,0,stream>>>(
                zbuf, vW2 + (size_t)l*2*HDIM*HDIM, vb2 + (size_t)l*HDIM, vfeat, B, 2*HDIM, HDIM);
            hipMemsetAsync(stats, 0, (size_t)2*HDIM*sizeof(double), stream);
            k_colstats<<<dim3(cdiv(B,256),1),320,0,stream>>>(vfeat, B, HDIM, 256, stats);
            k_bn_finalize<<<1,320,0,stream>>>(stats, vg2 + (size_t)l*HDIM, vbt2 + (size_t)l*HDIM,
                                              HDIM, (float)B, ssv);
            k_bn_apply<HDIM><<<cdiv(BT,256),256,0,stream>>>(vfeat, ssv, BT, 1);
            // X_{l+1} = relu(bn(out)) + vfeat[gid] ; also fills vsum for next layer
            hipMemsetAsync(vsum, 0, (size_t)BT*sizeof(float), stream);
            k_bnvf<<<cdiv(N*KP1,256),256,0,stream>>>(out, ssn, vfeat, gid, Xb, vsum, N);
        } else {
            k_bn_apply<HDIM><<<cdiv(NT,256),256,0,stream>>>(out, ssn, NT, 0);
        }
    }
}

// Round 7
// 4992.421 us; speedup vs baseline: 1.4584x; 1.0203x over previous
//
#include <hip/hip_runtime.h>
#include <hip/hip_bf16.h>

#define HDIM 300
#define FEAT 16
#define NL 5
#define BGR 4096
#define BNEPS 1e-5f
#define KP1 320   // K=300 padded to multiple of 32

typedef __attribute__((ext_vector_type(8))) short s8v;
typedef __attribute__((ext_vector_type(4))) float f4v;

__device__ __forceinline__ unsigned short f2bu(float f){
    __hip_bfloat16 h = __float2bfloat16(f);
    return __builtin_bit_cast(unsigned short, h);
}

// ---------------- setup kernels ----------------
__global__ void k_count_deg(const int* __restrict__ dst, int* __restrict__ cnt, int E){
    int e = blockIdx.x*blockDim.x + threadIdx.x;
    if (e < E) atomicAdd(&cnt[dst[e]], 1);
}
__global__ void k_deg(const int* __restrict__ cnt, float* __restrict__ degs, int N){
    int i = blockIdx.x*blockDim.x + threadIdx.x;
    if (i < N) degs[i] = (float)cnt[i] + 1.0f;
}
// --- exclusive scan of cnt -> off (off[N]=E), 3 phases ---
__global__ void k_scan_partial(const int* __restrict__ cnt, int* __restrict__ part, int N){
    __shared__ int sm[256];
    int i = blockIdx.x*256 + threadIdx.x;
    sm[threadIdx.x] = (i < N) ? cnt[i] : 0;
    __syncthreads();
    for (int s = 128; s > 0; s >>= 1){
        if (threadIdx.x < s) sm[threadIdx.x] += sm[threadIdx.x + s];
        __syncthreads();
    }
    if (threadIdx.x == 0) part[blockIdx.x] = sm[0];
}
__global__ void k_scan_blocks(int* __restrict__ part, int nb){
    __shared__ int sm[512];
    int t = threadIdx.x;
    int v = (t < nb) ? part[t] : 0;
    sm[t] = v; __syncthreads();
    for (int o = 1; o < 512; o <<= 1){
        int x = (t >= o) ? sm[t - o] : 0;
        __syncthreads();
        sm[t] += x;
        __syncthreads();
    }
    if (t < nb) part[t] = sm[t] - v;   // exclusive
}
__global__ void k_scan_final(const int* __restrict__ cnt, const int* __restrict__ part,
                             int* __restrict__ off, int N){
    __shared__ int sm[256];
    int i = blockIdx.x*256 + threadIdx.x;
    int v = (i < N) ? cnt[i] : 0;
    sm[threadIdx.x] = v; __syncthreads();
    for (int o = 1; o < 256; o <<= 1){
        int x = (threadIdx.x >= o) ? sm[threadIdx.x - o] : 0;
        __syncthreads();
        sm[threadIdx.x] += x;
        __syncthreads();
    }
    if (i < N){
        off[i] = part[blockIdx.x] + sm[threadIdx.x] - v;
        if (i == N-1) off[N] = part[blockIdx.x] + sm[threadIdx.x];
    }
}
__global__ void k_fill(const int* __restrict__ dst, const int* __restrict__ off,
                       int* __restrict__ fillc, int* __restrict__ eid, int E){
    int e = blockIdx.x*blockDim.x + threadIdx.x;
    if (e < E){
        int d = dst[e];
        int p = off[d] + atomicAdd(&fillc[d], 1);
        eid[p] = e;
    }
}
// permute src + edge_feats into CSR (dst-grouped) order
__global__ void k_permute(const int* __restrict__ eid, const int* __restrict__ src,
                          const float* __restrict__ ef,
                          int* __restrict__ srcp, float* __restrict__ efp, int E){
    int p = blockIdx.x*blockDim.x + threadIdx.x;
    if (p >= E) return;
    int e = eid[p];
    srcp[p] = src[e];
    const float4* s4 = (const float4*)(ef + (size_t)e*FEAT);
    float4* d4 = (float4*)(efp + (size_t)p*FEAT);
    d4[0] = s4[0]; d4[1] = s4[1]; d4[2] = s4[2]; d4[3] = s4[3];
}
// gid is sorted: gstart[g] = first node index with gid >= g ; gstart[B] = N
__global__ void k_gstart(const int* __restrict__ gid, int* __restrict__ gstart, int N, int B){
    int i = blockIdx.x*blockDim.x + threadIdx.x;
    if (i >= N) return;
    int prev = (i == 0) ? -1 : gid[i-1];
    int cur = gid[i];
    for (int g = prev + 1; g <= cur; g++) gstart[g] = i;
    if (i == N-1) for (int g = cur + 1; g <= B; g++) gstart[g] = N;
}
__global__ void k_init_vfeat(const float* __restrict__ vn, float* __restrict__ vfeat, int total){
    int t = blockIdx.x*blockDim.x + threadIdx.x;
    if (t < total) vfeat[t] = vn[t % HDIM];
}
// weight transpose+pad to bf16: Wt[n][kp] = W[k][n]
__global__ void k_wt(const float* __restrict__ W, unsigned short* __restrict__ Wt,
                     int K, int Ncol, int Kpad){
    int t = blockIdx.x*blockDim.x + threadIdx.x;
    if (t >= Ncol*Kpad) return;
    int n = t / Kpad, kp = t - n*Kpad;
    Wt[t] = (kp < K) ? f2bu(W[(size_t)kp*Ncol + n]) : (unsigned short)0;
}
// layer 0: X = emb[nt] + vfeat[gid]; write f32 X and padded bf16 Xb
__global__ void k_x0(const float* __restrict__ emb, const int* __restrict__ nt,
                     const float* __restrict__ vfeat, const int* __restrict__ gid,
                     float* __restrict__ X, unsigned short* __restrict__ Xb, int N){
    int t = blockIdx.x*blockDim.x + threadIdx.x;
    if (t >= N*KP1) return;
    int i = t / KP1, c = t - i*KP1;
    if (c < HDIM){
        float v = emb[nt[i]*HDIM + c] + vfeat[gid[i]*HDIM + c];
        X[(size_t)i*HDIM + c] = v;
        Xb[t] = f2bu(v);
    } else Xb[t] = 0;
}
// mid layers: X = relu(bn(X)) + vfeat[gid]; write f32 X and padded bf16 Xb
__global__ void k_bnvf(float* __restrict__ X, const float* __restrict__ ss,
                       const float* __restrict__ vfeat, const int* __restrict__ gid,
                       unsigned short* __restrict__ Xb, int N){
    int t = blockIdx.x*blockDim.x + threadIdx.x;
    if (t >= N*KP1) return;
    int i = t / KP1, c = t - i*KP1;
    if (c < HDIM){
        float v = X[(size_t)i*HDIM + c]*ss[c] + ss[HDIM + c];
        v = fmaxf(v, 0.f) + vfeat[gid[i]*HDIM + c];
        X[(size_t)i*HDIM + c] = v;
        Xb[t] = f2bu(v);
    } else Xb[t] = 0;
}
// per-graph segment sum (gid sorted -> contiguous ranges), no atomics:
// vsum[g] = sum_{i in graph g} X[i] + vfeat[g]
__global__ void k_vseg(const float* __restrict__ X, const float* __restrict__ vfeat,
                       const int* __restrict__ gstart, float* __restrict__ vsum){
    int g = blockIdx.x;
    int c = threadIdx.x;
    if (c >= HDIM) return;
    int r0 = gstart[g], r1 = gstart[g+1];
    float s = 0.f;
    for (int r = r0; r < r1; ++r) s += X[(size_t)r*HDIM + c];
    vsum[(size_t)g*HDIM + c] = s + vfeat[(size_t)g*HDIM + c];
}

// ---------------- MFMA bf16 GEMM: C = A@Wt^T + bias ----------------
__global__ __launch_bounds__(256) void k_gemm_mfma(
    const unsigned short* __restrict__ A, int lda,
    const unsigned short* __restrict__ Wt, int ldw,
    const float* __restrict__ bias,
    float* __restrict__ C, int M, int Kpad, int Ncol)
{
    __shared__ short As[128][40];
    __shared__ short Bs[64][40];
    int tid = threadIdx.x;
    int bm = blockIdx.x * 128;
    int bn = blockIdx.y * 64;
    int lane = tid & 63;
    int w = tid >> 6;
    int wm = w & 1, wn = w >> 1;
    int l15 = lane & 15, l4 = lane >> 4;
    f4v acc[4][2];
#pragma unroll
    for (int mi = 0; mi < 4; mi++)
#pragma unroll
        for (int ni = 0; ni < 2; ni++) acc[mi][ni] = (f4v){0.f,0.f,0.f,0.f};

    int arow = tid >> 1;
    int akc  = (tid & 1) * 2;
    int gmA  = bm + arow;
    int brow = tid >> 2;
    int bkc  = tid & 3;
    int gnB  = bn + brow;
    const s8v zv = (s8v){0,0,0,0,0,0,0,0};

    for (int k0 = 0; k0 < Kpad; k0 += 32){
        __syncthreads();
        s8v a0 = zv, a1 = zv;
        if (gmA < M){
            const s8v* ap = (const s8v*)(A + (size_t)gmA*lda + k0 + akc*8);
            a0 = ap[0]; a1 = ap[1];
        }
        *(s8v*)&As[arow][akc*8]     = a0;
        *(s8v*)&As[arow][akc*8 + 8] = a1;
        s8v b0 = zv;
        if (gnB < Ncol) b0 = *(const s8v*)(Wt + (size_t)gnB*ldw + k0 + bkc*8);
        *(s8v*)&Bs[brow][bkc*8] = b0;
        __syncthreads();

        s8v af[4], bf[2];
#pragma unroll
        for (int mi = 0; mi < 4; mi++) af[mi] = *(const s8v*)&As[wm*64 + mi*16 + l15][l4*8];
#pragma unroll
        for (int ni = 0; ni < 2; ni++) bf[ni] = *(const s8v*)&Bs[wn*32 + ni*16 + l15][l4*8];
#pragma unroll
        for (int mi = 0; mi < 4; mi++)
#pragma unroll
            for (int ni = 0; ni < 2; ni++)
                acc[mi][ni] = __builtin_amdgcn_mfma_f32_16x16x32_bf16(af[mi], bf[ni], acc[mi][ni], 0, 0, 0);
    }

#pragma unroll
    for (int ni = 0; ni < 2; ni++){
        int col = bn + wn*32 + ni*16 + l15;
        if (col >= Ncol) continue;
        float bia = bias[col];
#pragma unroll
        for (int mi = 0; mi < 4; mi++){
#pragma unroll
            for (int r = 0; r < 4; r++){
                int row = bm + wm*64 + mi*16 + l4*4 + r;
                if (row < M) C[(size_t)row*Ncol + col] = acc[mi][ni][r] + bia;
            }
        }
    }
}

// ---------------- f32 VALU GEMM (vnode path) ----------------
__global__ __launch_bounds__(256) void k_gemm(const float* __restrict__ A, const float* __restrict__ W,
                                              const float* __restrict__ bias, float* __restrict__ C,
                                              int M, int K, int Ncol){
    __shared__ float As[16][132];
    __shared__ float Ws[16][64];
    int tid = threadIdx.x;
    int bm = blockIdx.x * 128;
    int bn = blockIdx.y * 64;
    int tx = tid & 15;
    int ty = tid >> 4;
    float acc[8][4];
#pragma unroll
    for (int i = 0; i < 8; i++)
#pragma unroll
        for (int j = 0; j < 4; j++) acc[i][j] = 0.f;
    int ka  = tid & 15;
    int ra0 = tid >> 4;
    int colw = tid & 63;
    int kw0  = tid >> 6;
    for (int k0 = 0; k0 < K; k0 += 16){
#pragma unroll
        for (int j = 0; j < 8; j++){
            int r = ra0 + j*16;
            int gm = bm + r, gk = k0 + ka;
            As[ka][r] = (gm < M && gk < K) ? A[(size_t)gm*K + gk] : 0.f;
        }
#pragma unroll
        for (int j = 0; j < 4; j++){
            int kk = kw0 + j*4;
            int gk = k0 + kk, gn = bn + colw;
            Ws[kk][colw] = (gk < K && gn < Ncol) ? W[(size_t)gk*Ncol + gn] : 0.f;
        }
        __syncthreads();
#pragma unroll
        for (int kk = 0; kk < 16; kk++){
            float a[8], b[4];
#pragma unroll
            for (int i = 0; i < 8; i++) a[i] = As[kk][ty*8 + i];
#pragma unroll
            for (int j = 0; j < 4; j++) b[j] = Ws[kk][tx*4 + j];
#pragma unroll
            for (int i = 0; i < 8; i++)
#pragma unroll
                for (int j = 0; j < 4; j++) acc[i][j] += a[i]*b[j];
        }
        __syncthreads();
    }
    float bb[4];
#pragma unroll
    for (int j = 0; j < 4; j++){ int gn = bn + tx*4 + j; bb[j] = (gn < Ncol) ? bias[gn] : 0.f; }
#pragma unroll
    for (int i = 0; i < 8; i++){
        int gm = bm + ty*8 + i;
        if (gm < M){
#pragma unroll
            for (int j = 0; j < 4; j++){
                int gn = bn + tx*4 + j;
                if (gn < Ncol) C[(size_t)gm*Ncol + gn] = acc[i][j] + bb[j];
            }
        }
    }
}

// ---------------- CSR aggregation, We in VGPRs, persistent waves ----------------
// out[d] = relu(hp[d]+res)/deg[d] + sum_p rsqrt(deg[srcp]*deg[d]) * relu(hp[srcp] + efp@We + be)
__global__ __launch_bounds__(256) void k_agg(
    const float* __restrict__ hp, const float* __restrict__ res, const float* __restrict__ degs,
    const float* __restrict__ efp, const int* __restrict__ srcp, const int* __restrict__ off,
    const float* __restrict__ We, const float* __restrict__ be,
    float* __restrict__ out, int N)
{
    int lane = threadIdx.x & 63;
    // per-lane register copy of We columns (lane+64i), be, res — loaded once per wave
    float Wr[5][FEAT], bev[5], rev[5];
#pragma unroll
    for (int i = 0; i < 5; i++){
        int c = lane + 64*i;
        bool ok = (c < HDIM);
        bev[i] = ok ? be[c] : 0.f;
        rev[i] = ok ? res[c] : 0.f;
#pragma unroll
        for (int k = 0; k < FEAT; k++)
            Wr[i][k] = ok ? We[k*HDIM + c] : 0.f;
    }
    int wid = blockIdx.x*4 + (threadIdx.x >> 6);
    int nw = gridDim.x*4;
    for (int d = wid; d < N; d += nw){
        float dd = degs[d];
        const float* hrowd = hp + (size_t)d*HDIM;
        float acc[5];
#pragma unroll
        for (int i = 0; i < 5; i++){
            int c = lane + 64*i;
            acc[i] = (c < HDIM) ? fmaxf(hrowd[c] + rev[i], 0.f) / dd : 0.f;
        }
        int e0 = off[d], e1 = off[d+1];
        int p = e0;
        for (; p + 2 <= e1; p += 2){
            int s0 = srcp[p], s1 = srcp[p+1];
            float n0 = rsqrtf(degs[s0]*dd);
            float n1 = rsqrtf(degs[s1]*dd);
            const float4* q0 = (const float4*)(efp + (size_t)p*FEAT);
            const float4* q1 = (const float4*)(efp + (size_t)(p+1)*FEAT);
            float4 ea0 = q0[0], ea1 = q0[1], ea2 = q0[2], ea3 = q0[3];
            float4 fb0 = q1[0], fb1 = q1[1], fb2 = q1[2], fb3 = q1[3];
            float ev0[FEAT] = {ea0.x,ea0.y,ea0.z,ea0.w, ea1.x,ea1.y,ea1.z,ea1.w,
                               ea2.x,ea2.y,ea2.z,ea2.w, ea3.x,ea3.y,ea3.z,ea3.w};
            float ev1[FEAT] = {fb0.x,fb0.y,fb0.z,fb0.w, fb1.x,fb1.y,fb1.z,fb1.w,
                               fb2.x,fb2.y,fb2.z,fb2.w, fb3.x,fb3.y,fb3.z,fb3.w};
            const float* h0 = hp + (size_t)s0*HDIM;
            const float* h1 = hp + (size_t)s1*HDIM;
#pragma unroll
            for (int i = 0; i < 5; i++){
                int c = lane + 64*i;
                if (c < HDIM){
                    float hv0 = h0[c], hv1 = h1[c];
                    float m0 = bev[i], m1 = bev[i];
#pragma unroll
                    for (int k = 0; k < FEAT; k++){
                        m0 += ev0[k]*Wr[i][k];
                        m1 += ev1[k]*Wr[i][k];
                    }
                    acc[i] += fmaxf(hv0 + m0, 0.f)*n0 + fmaxf(hv1 + m1, 0.f)*n1;
                }
            }
        }
        if (p < e1){
            int s0 = srcp[p];
            float n0 = rsqrtf(degs[s0]*dd);
            const float4* q0 = (const float4*)(efp + (size_t)p*FEAT);
            float4 ea0 = q0[0], ea1 = q0[1], ea2 = q0[2], ea3 = q0[3];
            float ev0[FEAT] = {ea0.x,ea0.y,ea0.z,ea0.w, ea1.x,ea1.y,ea1.z,ea1.w,
                               ea2.x,ea2.y,ea2.z,ea2.w, ea3.x,ea3.y,ea3.z,ea3.w};
            const float* h0 = hp + (size_t)s0*HDIM;
#pragma unroll
            for (int i = 0; i < 5; i++){
                int c = lane + 64*i;
                if (c < HDIM){
                    float m0 = bev[i];
#pragma unroll
                    for (int k = 0; k < FEAT; k++) m0 += ev0[k]*Wr[i][k];
                    acc[i] += fmaxf(h0[c] + m0, 0.f)*n0;
                }
            }
        }
        float* orow = out + (size_t)d*HDIM;
#pragma unroll
        for (int i = 0; i < 5; i++){
            int c = lane + 64*i;
            if (c < HDIM) __builtin_nontemporal_store(acc[i], &orow[c]);
        }
    }
}

// ---------------- batchnorm: column stats (f64), finalize, apply ----------------
__global__ void k_colstats(const float* __restrict__ x, int rows, int cols, int rpb,
                           double* __restrict__ stats){
    int c = blockIdx.y*blockDim.x + threadIdx.x;
    if (c >= cols) return;
    int r0 = blockIdx.x * rpb;
    int r1 = min(rows, r0 + rpb);
    double s = 0.0, s2 = 0.0;
    for (int r = r0; r < r1; ++r){
        float v = x[(size_t)r*cols + c];
        s += v; s2 += (double)v*v;
    }
    unsafeAtomicAdd(&stats[c], s);
    unsafeAtomicAdd(&stats[cols + c], s2);
}
__global__ void k_bn_finalize(const double* __restrict__ stats, const float* __restrict__ g,
                              const float* __restrict__ b, int cols, float rowsf, float* __restrict__ ss){
    int c = blockIdx.x*blockDim.x + threadIdx.x;
    if (c < cols){
        float mean = (float)(stats[c] / rowsf);
        float var  = (float)(stats[cols + c] / rowsf) - mean*mean;
        var = fmaxf(var, 0.f);
        float sc = g[c] * rsqrtf(var + BNEPS);
        ss[c] = sc;
        ss[cols + c] = b[c] - mean*sc;
    }
}
template<int COLS>
__global__ void k_bn_apply(float* __restrict__ x, const float* __restrict__ ss, int total, int relu){
    int t = blockIdx.x*blockDim.x + threadIdx.x;
    if (t < total){
        int c = t % COLS;
        float v = x[t]*ss[c] + ss[COLS + c];
        if (relu) v = fmaxf(v, 0.f);
        x[t] = v;
    }
}

extern "C" void kernel_launch(void* const* d_in, const int* in_sizes, int n_in,
                              void* d_out, int out_size, void* d_ws, size_t ws_size,
                              hipStream_t stream){
    const int*   node_types = (const int*)d_in[0];
    const float* edge_feats = (const float*)d_in[1];
    const int*   src        = (const int*)d_in[2];
    const int*   dst        = (const int*)d_in[3];
    const int*   gid        = (const int*)d_in[4];
    const float* node_emb   = (const float*)d_in[6];
    const float* Wn         = (const float*)d_in[7];
    const float* bn_lin     = (const float*)d_in[8];
    const float* We         = (const float*)d_in[9];
    const float* be         = (const float*)d_in[10];
    const float* res_emb    = (const float*)d_in[11];
    const float* bn_gamma   = (const float*)d_in[12];
    const float* bn_beta    = (const float*)d_in[13];
    const float* vn_emb     = (const float*)d_in[14];
    const float* vW1        = (const float*)d_in[15];
    const float* vb1        = (const float*)d_in[16];
    const float* vg1        = (const float*)d_in[17];
    const float* vbt1       = (const float*)d_in[18];
    const float* vW2        = (const float*)d_in[19];
    const float* vb2        = (const float*)d_in[20];
    const float* vg2        = (const float*)d_in[21];
    const float* vbt2       = (const float*)d_in[22];

    const int N = in_sizes[0];
    const int E = in_sizes[2];
    const int B = BGR;
    float* out = (float*)d_out;          // X / agg / final h

    char* w = (char*)d_ws;
    float*  hp    = (float*)w;  w += (size_t)N*HDIM*sizeof(float);
    float*  degs  = (float*)w;  w += (size_t)N*sizeof(float);
    float*  vfeat = (float*)w;  w += (size_t)B*HDIM*sizeof(float);
    float*  vsum  = (float*)w;  w += (size_t)B*HDIM*sizeof(float);
    float*  zbuf  = (float*)w;  w += (size_t)B*2*HDIM*sizeof(float);
    double* stats = (double*)w; w += (size_t)2*2*HDIM*sizeof(double);
    float*  ssn   = (float*)w;  w += (size_t)2*HDIM*sizeof(float);
    float*  ssv   = (float*)w;  w += (size_t)2*2*HDIM*sizeof(float);
    int*    cnt   = (int*)w;    w += (size_t)N*sizeof(int);
    int*    coff  = (int*)w;    w += (size_t)(N+1)*sizeof(int);
    int*    fillc = (int*)w;    w += (size_t)N*sizeof(int);
    int*    eid   = (int*)w;    w += (size_t)E*sizeof(int);
    int*    part  = (int*)w;    w += (size_t)512*sizeof(int);
    int*    srcp  = (int*)w;    w += (size_t)E*sizeof(int);
    int*    gstart= (int*)w;    w += (size_t)(B+1)*sizeof(int);
    float*  efp   = (float*)w;  w += (size_t)E*FEAT*sizeof(float);
    unsigned short* Xb  = (unsigned short*)w; w += (size_t)N*KP1*sizeof(unsigned short);
    unsigned short* Wnb = (unsigned short*)w; w += (size_t)NL*HDIM*KP1*sizeof(unsigned short);

    const int NT = N*HDIM;
    const int BT = B*HDIM;
    auto cdiv = [](int a, int b){ return (a + b - 1)/b; };
    const int nb = cdiv(N, 256);

    // ---- setup: degrees + CSR + permuted edge data + graph ranges ----
    (void)hipMemsetAsync(cnt, 0, (size_t)N*sizeof(int), stream);
    k_count_deg<<<cdiv(E,256),256,0,stream>>>(dst, cnt, E);
    k_deg<<<nb,256,0,stream>>>(cnt, degs, N);
    k_scan_partial<<<nb,256,0,stream>>>(cnt, part, N);
    k_scan_blocks<<<1,512,0,stream>>>(part, nb);
    k_scan_final<<<nb,256,0,stream>>>(cnt, part, coff, N);
    (void)hipMemsetAsync(fillc, 0, (size_t)N*sizeof(int), stream);
    k_fill<<<cdiv(E,256),256,0,stream>>>(dst, coff, fillc, eid, E);
    k_permute<<<cdiv(E,256),256,0,stream>>>(eid, src, edge_feats, srcp, efp, E);
    k_gstart<<<nb,256,0,stream>>>(gid, gstart, N, B);
    // ---- setup: weights, vfeat, X0 ----
    k_init_vfeat<<<cdiv(BT,256),256,0,stream>>>(vn_emb, vfeat, BT);
    for (int l = 0; l < NL; l++)
        k_wt<<<cdiv(HDIM*KP1,256),256,0,stream>>>(Wn + (size_t)l*HDIM*HDIM,
                                                  Wnb + (size_t)l*HDIM*KP1, HDIM, HDIM, KP1);
    k_x0<<<cdiv(N*KP1,256),256,0,stream>>>(node_emb, node_types, vfeat, gid, out, Xb, N);

    for (int l = 0; l < NL; l++){
        // vnode segment sum of X (before k_agg destroys X in `out`)
        if (l < NL-1)
            k_vseg<<<B,320,0,stream>>>(out, vfeat, gstart, vsum);
        // hp = Xb @ Wn[l] + bn_lin[l]
        k_gemm_mfma<<<dim3(cdiv(N,128), cdiv(HDIM,64)),256,0,stream>>>(
            Xb, KP1, Wnb + (size_t)l*HDIM*KP1, KP1, bn_lin + (size_t)l*HDIM, hp, N, KP1, HDIM);
        // out = residual + CSR-aggregated edge messages
        k_agg<<<2048,256,0,stream>>>(hp, res_emb + (size_t)l*HDIM, degs,
                                     efp, srcp, coff,
                                     We + (size_t)l*FEAT*HDIM, be + (size_t)l*HDIM, out, N);
        // node BN stats
        (void)hipMemsetAsync(stats, 0, (size_t)2*HDIM*sizeof(double), stream);
        k_colstats<<<dim3(cdiv(N,256),1),320,0,stream>>>(out, N, HDIM, 256, stats);
        k_bn_finalize<<<1,320,0,stream>>>(stats, bn_gamma + (size_t)l*HDIM, bn_beta + (size_t)l*HDIM,
                                          HDIM, (float)N, ssn);
        if (l < NL-1){
            // virtual-node MLP (vsum = segsum(X) + vfeat from k_vseg)
            k_gemm<<<dim3(cdiv(B,128), cdiv(2*HDIM,64)),256,0,stream>>>(
                vsum, vW1 + (size_t)l*HDIM*2*HDIM, vb1 + (size_t)l*2*HDIM, zbuf, B, HDIM, 2*HDIM);
            (void)hipMemsetAsync(stats, 0, (size_t)2*2*HDIM*sizeof(double), stream);
            k_colstats<<<dim3(cdiv(B,256),2),320,0,stream>>>(zbuf, B, 2*HDIM, 256, stats);
            k_bn_finalize<<<1,640,0,stream>>>(stats, vg1 + (size_t)l*2*HDIM, vbt1 + (size_t)l*2*HDIM,
                                              2*HDIM, (float)B, ssv);
            k_bn_apply<2*HDIM><<<cdiv(B*2*HDIM,256),256,0,stream>>>(zbuf, ssv, B*2*HDIM, 1);
            k_gemm<<<dim3(cdiv(B,128), cdiv(HDIM,64)),256,0,stream>>>(
                zbuf, vW2 + (size_t)l*2*HDIM*HDIM, vb2 + (size_t)l*HDIM, vfeat, B, 2*HDIM, HDIM);
            (void)hipMemsetAsync(stats, 0, (size_t)2*HDIM*sizeof(double), stream);
            k_colstats<<<dim3(cdiv(B,256),1),320,0,stream>>>(vfeat, B, HDIM, 256, stats);
            k_bn_finalize<<<1,320,0,stream>>>(stats, vg2 + (size_t)l*HDIM, vbt2 + (size_t)l*HDIM,
                                              HDIM, (float)B, ssv);
            k_bn_apply<HDIM><<<cdiv(BT,256),256,0,stream>>>(vfeat, ssv, BT, 1);
            // X_{l+1} = relu(bn(out)) + vfeat[gid]  (writes f32 X and bf16 Xb)
            k_bnvf<<<cdiv(N*KP1,256),256,0,stream>>>(out, ssn, vfeat, gid, Xb, N);
        } else {
            k_bn_apply<HDIM><<<cdiv(NT,256),256,0,stream>>>(out, ssn, NT, 0);
        }
    }
}